// Round 1
// baseline (992.361 us; speedup 1.0000x reference)
//
#include <hip/hip_runtime.h>
#include <hip/hip_bf16.h>

// DeformableConv1D: B=4, Cin=256, Cout=256, L=8192, K=7, stride=1, pad=3, dil=1
// out_len = 8192. Reference semantics:
//   loc[b,l,k] = l + k + (offset_conv(x)[b,l,k] + offset_b[k])
//   x0 = floor(loc); x0c/x1c clamped to [0, L-1]
//   wa = x1c - loc; wb = loc - x0c
//   interp = wa*x[b,i,x0c] + wb*x[b,i,x1c]
//   out[b,o,l] = sum_{i,k} interp[b,i,l,k]*w[o,i,k] + bias[o]

#define B_    4
#define CIN   256
#define COUT  256
#define LEN   8192
#define KK    7
#define NTOT  (B_ * LEN)          // 32768 (b,l) pairs

// main-kernel tiling
#define CI      8                 // input channels per K-chunk
#define KC      (CI * KK)         // 56 contraction indices per chunk
#define NCHUNK  (CIN / CI)        // 32 chunks
#define MT      64                // o-tile
#define NT      128               // n-tile

// ---------------------------------------------------------------------------
// Kernel 1: offset conv -> sampling locations loc[b,l,k] (float), ws array.
// One thread per (b,l). offset_w accessed with wave-uniform indices -> s_load.
// ---------------------------------------------------------------------------
__global__ __launch_bounds__(256) void loc_kernel(
    const float* __restrict__ X, const float* __restrict__ OW,
    const float* __restrict__ OB, float* __restrict__ Loc) {
  int id = blockIdx.x * 256 + threadIdx.x;   // grid = 128 blocks -> 32768
  int b = id >> 13;
  int l = id & (LEN - 1);

  float acc[KK];
#pragma unroll
  for (int k = 0; k < KK; ++k) acc[k] = OB[k];

  const float* xb = X + (size_t)b * CIN * LEN;
  for (int i = 0; i < CIN; ++i) {
    const float* xr = xb + i * LEN;
    float xv[KK];
#pragma unroll
    for (int j = 0; j < KK; ++j) {
      int pos = l + j - 3;                      // pad = 3, zero outside
      xv[j] = (pos >= 0 && pos < LEN) ? xr[pos] : 0.0f;
    }
#pragma unroll
    for (int k = 0; k < KK; ++k) {
#pragma unroll
      for (int j = 0; j < KK; ++j) {
        acc[k] += xv[j] * OW[(k * CIN + i) * KK + j];  // uniform -> s_load
      }
    }
  }
#pragma unroll
  for (int k = 0; k < KK; ++k) {
    Loc[(size_t)id * KK + k] = (float)(l + k) + acc[k];
  }
}

// ---------------------------------------------------------------------------
// Kernel 2: transpose weight (o, i, k) -> Wt[(i*7+k)*256 + o] for coalesced
// staging in the main GEMM.
// ---------------------------------------------------------------------------
__global__ __launch_bounds__(256) void wt_kernel(
    const float* __restrict__ W, float* __restrict__ Wt) {
  int idx = blockIdx.x * 256 + threadIdx.x;    // grid = 1792 blocks -> 458752
  if (idx >= COUT * CIN * KK) return;
  int q = idx >> 8;          // contraction index (i*7+k)
  int o = idx & 255;
  Wt[idx] = W[o * (CIN * KK) + q];
}

// ---------------------------------------------------------------------------
// Kernel 3: main GEMM  C[o, n] = sum_q Wt[q][o] * interp[q][n],  n = b*8192+l.
// Block: 64 o x 128 n, 256 threads, 4x8 register tile.
// interp built on the fly into LDS per 56-wide K-chunk.
// ---------------------------------------------------------------------------
__global__ __launch_bounds__(256) void main_kernel(
    const float* __restrict__ X, const float* __restrict__ Wt,
    const float* __restrict__ Bias, const float* __restrict__ Loc,
    float* __restrict__ Out) {
  __shared__ float Wl[KC][MT];     // 14 KB
  __shared__ float Il[KC][NT];     // 28 KB

  const int t  = threadIdx.x;
  const int ty = t >> 4;           // 0..15 -> o groups of 4
  const int tx = t & 15;           // 0..15 -> n groups of 8
  const int n0 = blockIdx.x * NT;  // gridDim.x = 256
  const int o0 = blockIdx.y * MT;  // gridDim.y = 4

  float acc[4][8];
#pragma unroll
  for (int a = 0; a < 4; ++a)
#pragma unroll
    for (int c = 0; c < 8; ++c) acc[a][c] = 0.0f;

  for (int ch = 0; ch < NCHUNK; ++ch) {
    const int ic0 = ch * CI;
    __syncthreads();  // protect LDS from previous iteration's readers

    // stage W chunk: KC*MT = 3584 elems, 14 per thread, coalesced
    for (int e = t; e < KC * MT; e += 256) {
      int q  = e >> 6;
      int oo = e & 63;
      Wl[q][oo] = Wt[(ic0 * KK + q) * COUT + o0 + oo];
    }

    // stage interp chunk: KC*NT = 7168 elems, 28 per thread
    for (int e = t; e < KC * NT; e += 256) {
      int q  = e >> 7;
      int nn = e & 127;
      int i  = ic0 + q / KK;
      int k  = q % KK;
      int n  = n0 + nn;
      int b  = n >> 13;
      int l  = n & (LEN - 1);
      (void)l;
      float locv = Loc[(size_t)n * KK + k];
      float fl = floorf(locv);
      int x0 = (int)fl;
      int x1 = x0 + 1;
      int x0c = min(max(x0, 0), LEN - 1);
      int x1c = min(max(x1, 0), LEN - 1);
      float wa = (float)x1c - locv;
      float wb = locv - (float)x0c;
      const float* xr = X + ((size_t)(b * CIN + i) << 13);
      Il[q][nn] = wa * xr[x0c] + wb * xr[x1c];
    }
    __syncthreads();

    // compute: 56 q-steps, 32 FMA each
#pragma unroll 8
    for (int q = 0; q < KC; ++q) {
      float wf[4], ifr[8];
      *(float4*)wf        = *(const float4*)&Wl[q][ty * 4];
      *(float4*)&ifr[0]   = *(const float4*)&Il[q][tx * 8];
      *(float4*)&ifr[4]   = *(const float4*)&Il[q][tx * 8 + 4];
#pragma unroll
      for (int a = 0; a < 4; ++a)
#pragma unroll
        for (int c = 0; c < 8; ++c) acc[a][c] += wf[a] * ifr[c];
    }
  }

  // epilogue: add bias, write fp32 out[b][o][l]
  const int n = n0 + tx * 8;       // 8 consecutive n, same b (aligned)
  const int b = n >> 13;
  const int l = n & (LEN - 1);
#pragma unroll
  for (int a = 0; a < 4; ++a) {
    int o = o0 + ty * 4 + a;
    float bv = Bias[o];
    float* orow = Out + (((size_t)(b * COUT + o)) << 13) + l;
    float4 v0 = {acc[a][0] + bv, acc[a][1] + bv, acc[a][2] + bv, acc[a][3] + bv};
    float4 v1 = {acc[a][4] + bv, acc[a][5] + bv, acc[a][6] + bv, acc[a][7] + bv};
    *(float4*)orow       = v0;
    *(float4*)(orow + 4) = v1;
  }
}

extern "C" void kernel_launch(void* const* d_in, const int* in_sizes, int n_in,
                              void* d_out, int out_size, void* d_ws, size_t ws_size,
                              hipStream_t stream) {
  const float* X    = (const float*)d_in[0];   // (4,256,8192)
  const float* W    = (const float*)d_in[1];   // (256,256,7)
  const float* Bias = (const float*)d_in[2];   // (256,)
  const float* OW   = (const float*)d_in[3];   // (7,256,7)
  const float* OB   = (const float*)d_in[4];   // (7,)
  float* Out = (float*)d_out;                  // (4,256,8192)

  float* Loc = (float*)d_ws;                   // 229376 floats (~0.9 MB)
  float* Wt  = Loc + (size_t)NTOT * KK;        // 458752 floats (~1.8 MB)

  loc_kernel<<<NTOT / 256, 256, 0, stream>>>(X, OW, OB, Loc);
  wt_kernel<<<(COUT * CIN * KK + 255) / 256, 256, 0, stream>>>(W, Wt);

  dim3 grid(NTOT / NT, COUT / MT);             // (256, 4)
  main_kernel<<<grid, 256, 0, stream>>>(X, Wt, Bias, Loc, Out);
}

// Round 2
// 273.915 us; speedup vs baseline: 3.6229x; 3.6229x over previous
//
#include <hip/hip_runtime.h>
#include <hip/hip_bf16.h>

// DeformableConv1D: B=4, Cin=256, Cout=256, L=8192, K=7, stride=1, pad=3, dil=1
// out[b,o,l] = sum_{i,kt} w[o,i,kt] * interp(b, l, i, kt) + bias[o]
// loc[b,l,kt] = l + kt + (offset_conv(x)[b,l,kt] + offset_b[kt])
// interp = wa*x[b,i,x0c] + wb*x[b,i,x1c]  (clamped lerp, reference formula)
//
// GEMM view: C[o, n] = sum_{q'} A[o][q'] * B[q'][n], n = b*8192+l,
// contraction REORDERED as q' = kt*256 + i  (kt outer -> compile-time per
// unrolled section; sampling table per (n,kt) lives in registers).

#define B_    4
#define CIN   256
#define COUT  256
#define LEN   8192
#define KK    7
#define NTOT  (B_ * LEN)          // 32768
#define QTOT  (CIN * KK)          // 1792
#define NCH   56                  // K-chunks of 32

typedef short s16x8 __attribute__((ext_vector_type(8)));
typedef float f32x4 __attribute__((ext_vector_type(4)));

static __device__ __forceinline__ unsigned short f2bf(float f) {
  union { float f; unsigned u; } u; u.f = f;
  unsigned r = u.u + 0x7FFF + ((u.u >> 16) & 1);   // RNE (finite inputs)
  return (unsigned short)(r >> 16);
}

// ---------------------------------------------------------------------------
// Kernel 1: Loc[n*7+k] = (l + k) + OB[k]   (base locations; offsets added by
// loc_partial via atomics). 229376 elems.
// ---------------------------------------------------------------------------
__global__ __launch_bounds__(256) void init_loc(
    const float* __restrict__ OB, float* __restrict__ Loc) {
  int id = blockIdx.x * 256 + threadIdx.x;     // grid 896
  int n = id / 7;
  int k = id - n * 7;
  int l = n & (LEN - 1);
  Loc[id] = (float)(l + k) + OB[k];
}

// ---------------------------------------------------------------------------
// Kernel 2: offset conv partials. 16 channel-groups of 16, atomicAdd into Loc.
// grid = 128*16 = 2048 blocks; g is block-uniform -> OW via s_loads.
// ---------------------------------------------------------------------------
__global__ __launch_bounds__(256) void loc_partial(
    const float* __restrict__ X, const float* __restrict__ OW,
    float* __restrict__ Loc) {
  int g = blockIdx.x >> 7;                               // 0..15
  int n = ((blockIdx.x & 127) << 8) + threadIdx.x;       // 0..32767
  int b = n >> 13;
  int l = n & (LEN - 1);
  const float* xb = X + ((size_t)b << 21);               // b*256*8192

  float acc[KK];
#pragma unroll
  for (int k = 0; k < KK; ++k) acc[k] = 0.0f;

  for (int i = g * 16; i < g * 16 + 16; ++i) {
    const float* xr = xb + ((size_t)i << 13);
    float xv[KK];
#pragma unroll
    for (int j = 0; j < KK; ++j) {
      int pos = l + j - 3;
      xv[j] = ((unsigned)pos < LEN) ? xr[pos] : 0.0f;
    }
#pragma unroll
    for (int k = 0; k < KK; ++k)
#pragma unroll
      for (int j = 0; j < KK; ++j)
        acc[k] += xv[j] * OW[(k * CIN + i) * KK + j];    // uniform -> s_load
  }
#pragma unroll
  for (int k = 0; k < KK; ++k)
    atomicAdd(Loc + (size_t)n * KK + k, acc[k]);
}

// ---------------------------------------------------------------------------
// Kernel 3: weights -> bf16 A-fragments in exact per-lane MFMA order.
// Wf[((ot*56 + c)*64 + ln)*8 + j] = bf16( W[o=ot*16+(ln&15)][i*7 + kt] )
//   where q' = c*32 + (ln>>4)*8 + j, kt = q'>>8, i = q'&255.
// ---------------------------------------------------------------------------
__global__ __launch_bounds__(256) void wt_build(
    const float* __restrict__ W, unsigned short* __restrict__ Wf) {
  int tid = blockIdx.x * 256 + threadIdx.x;    // grid 224 -> 57344 threads
  int ln = tid & 63;
  int oc = tid >> 6;                           // ot*56 + c
  int c  = oc % NCH;
  int ot = oc / NCH;
  int o  = ot * 16 + (ln & 15);
  int kb = c * 32 + (ln >> 4) * 8;
  s16x8 v;
#pragma unroll
  for (int j = 0; j < 8; ++j) {
    int q  = kb + j;
    int kt = q >> 8;
    int i  = q & 255;
    v[j] = (short)f2bf(W[(size_t)o * QTOT + i * KK + kt]);
  }
  *(s16x8*)(Wf + (size_t)tid * 8) = v;
}

// ---------------------------------------------------------------------------
// Kernel 4: main MFMA GEMM. Block = 256(o) x 64(n), 4 waves, 512 blocks.
// Wave w: o in [64w, 64w+64) as 4 o-tiles; 4 n-tiles of 16.
// Per chunk (K=32): stage interp to LDS (each thread 8 values, one b128
// write), read B-frags (b128, bank-spread rows of 80 B), A-frags direct
// from global (coalesced dwordx4), 16 mfma.
// ---------------------------------------------------------------------------
__global__ __launch_bounds__(256, 2) void main_kernel(
    const float* __restrict__ X, const unsigned short* __restrict__ Wf,
    const float* __restrict__ Bias, const float* __restrict__ Loc,
    float* __restrict__ Out) {
  __shared__ unsigned short Il[64][40];   // 64 n x 32 q, pad to 40 (80 B rows)

  const int t    = threadIdx.x;
  const int lane = t & 63;
  const int w    = t >> 6;
  const int n0   = blockIdx.x << 6;            // grid 512
  const int b    = n0 >> 13;
  const float* Xb = X + ((size_t)b << 21);

  // per-thread sampling table for n = n0+lane, all 7 taps -> registers
  int   x0i[KK], x1i[KK];
  float wav[KK], wbv[KK];
#pragma unroll
  for (int kt = 0; kt < KK; ++kt) {
    float locv = Loc[(size_t)(n0 + lane) * KK + kt];
    int x0  = (int)floorf(locv);
    int x0c = min(max(x0, 0), LEN - 1);
    int x1c = min(max(x0 + 1, 0), LEN - 1);
    x0i[kt] = x0c; x1i[kt] = x1c;
    wav[kt] = (float)x1c - locv;
    wbv[kt] = locv - (float)x0c;
  }

  f32x4 acc[4][4];
#pragma unroll
  for (int a = 0; a < 4; ++a)
#pragma unroll
    for (int c = 0; c < 4; ++c) acc[a][c] = (f32x4){0.f, 0.f, 0.f, 0.f};

  const int qb   = w * 8;         // this thread's q-quarter within chunk
  const int mrow = lane & 15;
  const int quad = lane >> 4;

#pragma unroll
  for (int kt = 0; kt < KK; ++kt) {            // kt compile-time in body
    const int   xo0 = x0i[kt], xo1 = x1i[kt];
    const float wa = wav[kt],  wb = wbv[kt];
    for (int s = 0; s < 8; ++s) {
      const int c = kt * 8 + s;
      __syncthreads();                         // previous readers done
      s16x8 v;
#pragma unroll
      for (int j = 0; j < 8; ++j) {
        const float* xr = Xb + ((size_t)(s * 32 + qb + j) << 13);
        float fa = xr[xo0];
        float fb = xr[xo1];
        v[j] = (short)f2bf(wa * fa + wb * fb);
      }
      *(s16x8*)&Il[lane][qb] = v;
      __syncthreads();                         // staging visible

      s16x8 bf[4];
#pragma unroll
      for (int nt = 0; nt < 4; ++nt)
        bf[nt] = *(const s16x8*)&Il[nt * 16 + mrow][quad * 8];

#pragma unroll
      for (int tt = 0; tt < 4; ++tt) {
        const s16x8 af =
            *(const s16x8*)(Wf + ((size_t)(((w * 4 + tt) * NCH + c) * 64 + lane) << 3));
        acc[tt][0] = __builtin_amdgcn_mfma_f32_16x16x32_bf16(af, bf[0], acc[tt][0], 0, 0, 0);
        acc[tt][1] = __builtin_amdgcn_mfma_f32_16x16x32_bf16(af, bf[1], acc[tt][1], 0, 0, 0);
        acc[tt][2] = __builtin_amdgcn_mfma_f32_16x16x32_bf16(af, bf[2], acc[tt][2], 0, 0, 0);
        acc[tt][3] = __builtin_amdgcn_mfma_f32_16x16x32_bf16(af, bf[3], acc[tt][3], 0, 0, 0);
      }
    }
  }

  // epilogue: D[m][n] -> m = quad*4+r (o), n = mrow (l); add bias, fp32 out
  const int lbase = (n0 & (LEN - 1)) + mrow;
#pragma unroll
  for (int tt = 0; tt < 4; ++tt) {
    const int obase = (w * 4 + tt) * 16 + quad * 4;
#pragma unroll
    for (int r = 0; r < 4; ++r) {
      const int o = obase + r;
      const float bv = Bias[o];
      float* orow = Out + (((size_t)(b * COUT + o)) << 13) + lbase;
#pragma unroll
      for (int nt = 0; nt < 4; ++nt)
        orow[nt * 16] = acc[tt][nt][r] + bv;
    }
  }
}

extern "C" void kernel_launch(void* const* d_in, const int* in_sizes, int n_in,
                              void* d_out, int out_size, void* d_ws, size_t ws_size,
                              hipStream_t stream) {
  const float* X    = (const float*)d_in[0];   // (4,256,8192)
  const float* W    = (const float*)d_in[1];   // (256,256,7)
  const float* Bias = (const float*)d_in[2];   // (256,)
  const float* OW   = (const float*)d_in[3];   // (7,256,7)
  const float* OB   = (const float*)d_in[4];   // (7,)
  float* Out = (float*)d_out;                  // (4,256,8192)

  float* Loc = (float*)d_ws;                            // 229376 f32
  unsigned short* Wf = (unsigned short*)(Loc + (size_t)NTOT * KK);  // 458752 bf16

  init_loc<<<NTOT * KK / 256, 256, 0, stream>>>(OB, Loc);
  loc_partial<<<128 * 16, 256, 0, stream>>>(X, OW, Loc);
  wt_build<<<COUT * QTOT / 8 / 256, 256, 0, stream>>>(W, Wf);
  main_kernel<<<NTOT / 64, 256, 0, stream>>>(X, Wf, Bias, Loc, Out);
}